// Round 8
// baseline (83.440 us; speedup 1.0000x reference)
//
#include <hip/hip_runtime.h>

// PhaseLinear: out[b,o] = sum_c coef[b,c] * (sum_i in[b,i]*W[c,o,i] + bias[c,o])
// All-f32 in / f32 out (verified r4), bf16 MFMA internally (absmax 0.031).
// Round 8: single fused kernel (drop r7's cvt dispatch: -1 launch node,
// -3 MB ws writes, no serial dependency). Direct f32 fragment loads +
// in-register cvt, r7's spill-proof ping-pong (#pragma unroll 1, peak live
// ~160 VGPR). Tile BM=64 x BO=32, 256 thr, grid (16,16)=256 blocks (1/CU).

#define BATCH 1024
#define IN_F  512
#define OUT_F 512

constexpr int BM = 64;            // batch rows per block (2 waves x 2 m-frags)
constexpr int BO = 32;            // out features per block (2 waves x 16)
constexpr int BK = 32;            // K per MFMA step
constexpr int KITERS = IN_F / BK; // 16

typedef __bf16 bf16x8 __attribute__((ext_vector_type(8)));
typedef float  f32x4  __attribute__((ext_vector_type(4)));
typedef float  f32x8  __attribute__((ext_vector_type(8)));

__device__ __forceinline__ bf16x8 cvt8(f32x8 v) {   // RNE, v_cvt_pk_bf16_f32
  bf16x8 r;
#pragma unroll
  for (int i = 0; i < 8; ++i) r[i] = (__bf16)v[i];
  return r;
}

struct Frag { f32x8 a0, a1, w0, w1, w2, w3; };      // 48 VGPRs

__global__ __launch_bounds__(256)
void PhaseLinear_kernel(const float* __restrict__ inp, const float* __restrict__ ph,
                        const float* __restrict__ wts, const float* __restrict__ bia,
                        float* __restrict__ outp) {
  __shared__ float sCoef[BM][4];

  const int tid = threadIdx.x;
  const int wv  = tid >> 6;        // wave 0..3
  const int wm  = wv & 1;          // m-half (32 rows)
  const int wo  = wv >> 1;         // o-half (16 outs)
  const int l   = tid & 63;
  const int o0  = blockIdx.x * BO;
  const int b0  = blockIdx.y * BM;

  // --- spline coefficients (replicates reference tt=[1,t^2,t^3,0] bug) ---
  if (tid < BM) {
    const float PI = 3.14159265358979323846f;
    float p  = ph[b0 + tid];
    float t  = (p < 1.5f * PI) ? (p / (1.5f * PI)) : ((p - 0.5f * PI) / (1.5f * PI));
    float t2 = t * t, t3 = t2 * t;
    sCoef[tid][0] = t3 - 0.5f * t2;        // tt @ (0.5*CATMULL_ROM_BASIS)
    sCoef[tid][1] = 1.0f - 2.5f * t3;
    sCoef[tid][2] = 0.5f * t2 + 2.0f * t3;
    sCoef[tid][3] = -0.5f * t3;
  }
  __syncthreads();                 // only barrier in the kernel

  const int n = l & 15;            // M index (A) / N index (B) / col of C
  const int q = l >> 4;            // k-quad, k-span q*8..q*8+8

  // per-lane global fragment pointers (32B contiguous each)
  const float* pa0 = inp + (size_t)(b0 + wm * 32 + n) * IN_F + q * 8;
  const float* pa1 = pa0 + (size_t)16 * IN_F;
  const float* pw[4];
#pragma unroll
  for (int c = 0; c < 4; ++c)
    pw[c] = wts + ((size_t)c * OUT_F + o0 + wo * 16 + n) * IN_F + q * 8;

  auto load6 = [&](int kk) -> Frag {
    const int off = kk * BK;
    Frag f;
    f.a0 = *(const f32x8*)(pa0 + off);
    f.a1 = *(const f32x8*)(pa1 + off);
    f.w0 = *(const f32x8*)(pw[0] + off);
    f.w1 = *(const f32x8*)(pw[1] + off);
    f.w2 = *(const f32x8*)(pw[2] + off);
    f.w3 = *(const f32x8*)(pw[3] + off);
    return f;
  };

  f32x4 acc[2][4];                 // [m-frag][ctrl-pt]
#pragma unroll
  for (int m = 0; m < 2; ++m)
#pragma unroll
    for (int c = 0; c < 4; ++c) acc[m][c] = (f32x4){0.f, 0.f, 0.f, 0.f};

  auto mfma6 = [&](const Frag& f) {
    bf16x8 a0 = cvt8(f.a0), a1 = cvt8(f.a1);
    bf16x8 w0 = cvt8(f.w0), w1 = cvt8(f.w1), w2 = cvt8(f.w2), w3 = cvt8(f.w3);
    acc[0][0] = __builtin_amdgcn_mfma_f32_16x16x32_bf16(a0, w0, acc[0][0], 0, 0, 0);
    acc[1][0] = __builtin_amdgcn_mfma_f32_16x16x32_bf16(a1, w0, acc[1][0], 0, 0, 0);
    acc[0][1] = __builtin_amdgcn_mfma_f32_16x16x32_bf16(a0, w1, acc[0][1], 0, 0, 0);
    acc[1][1] = __builtin_amdgcn_mfma_f32_16x16x32_bf16(a1, w1, acc[1][1], 0, 0, 0);
    acc[0][2] = __builtin_amdgcn_mfma_f32_16x16x32_bf16(a0, w2, acc[0][2], 0, 0, 0);
    acc[1][2] = __builtin_amdgcn_mfma_f32_16x16x32_bf16(a1, w2, acc[1][2], 0, 0, 0);
    acc[0][3] = __builtin_amdgcn_mfma_f32_16x16x32_bf16(a0, w3, acc[0][3], 0, 0, 0);
    acc[1][3] = __builtin_amdgcn_mfma_f32_16x16x32_bf16(a1, w3, acc[1][3], 0, 0, 0);
  };

  // ping-pong prefetch, unroll capped: peak live = 2 frag sets (~96 VGPR)
  Frag cur = load6(0);
#pragma unroll 1
  for (int kk = 0; kk < KITERS; kk += 2) {
    Frag nxt = load6(kk + 1);              // kk+1 <= 15, always valid
    mfma6(cur);
    if (kk + 2 < KITERS) cur = load6(kk + 2);
    mfma6(nxt);
  }

  // --- epilogue: blend 4 control points + bias, f32 store ---
  // C/D layout (m89/m91 verified): col = l&15, row = (l>>4)*4 + reg
  const int o = o0 + wo * 16 + n;
  float bs[4];
#pragma unroll
  for (int c = 0; c < 4; ++c) bs[c] = bia[c * OUT_F + o];

#pragma unroll
  for (int mf = 0; mf < 2; ++mf) {
#pragma unroll
    for (int r = 0; r < 4; ++r) {
      const int bl = wm * 32 + mf * 16 + q * 4 + r;
      float v = 0.f;
#pragma unroll
      for (int c = 0; c < 4; ++c)
        v += sCoef[bl][c] * (acc[mf][c][r] + bs[c]);
      outp[(size_t)(b0 + bl) * OUT_F + o] = v;
    }
  }
}

extern "C" void kernel_launch(void* const* d_in, const int* in_sizes, int n_in,
                              void* d_out, int out_size, void* d_ws, size_t ws_size,
                              hipStream_t stream) {
  const float* inp = (const float*)d_in[0];   // input  (1024, 512) f32
  const float* ph  = (const float*)d_in[1];   // phase  (1024,)     f32
  const float* wts = (const float*)d_in[2];   // weights(4,512,512) f32
  const float* bia = (const float*)d_in[3];   // biases (4,512)     f32
  float* outp = (float*)d_out;                // out    (1024,512)  f32

  dim3 grid(OUT_F / BO, BATCH / BM);          // (16, 16) = 256 blocks, 1/CU
  PhaseLinear_kernel<<<grid, 256, 0, stream>>>(inp, ph, wts, bia, outp);
}

// Round 9
// 72.657 us; speedup vs baseline: 1.1484x; 1.1484x over previous
//
#include <hip/hip_runtime.h>

// PhaseLinear: out[b,o] = sum_c coef[b,c] * (sum_i in[b,i]*W[c,o,i] + bias[c,o])
// All-f32 in / f32 out, bf16 MFMA internally (absmax 0.031).
// Round 9: r4's LDS-staged structure (fastest measured: coalesced staging
// decouples global latency from MFMA) with HALVED tile (BO=32) and DOUBLED
// grid: 512 blocks = 2 blocks/CU = 8 waves/CU -> co-resident block overlap
// hides staging stalls that r4's 1 block/CU exposed.

#define BATCH 1024
#define IN_F  512
#define OUT_F 512

constexpr int BM = 32;                       // batch rows per block
constexpr int BO = 32;                       // out features per block
constexpr int BK = 32;                       // K per stage
constexpr int KITERS = IN_F / BK;            // 16
constexpr int A_ELEMS = BM * BK;             // 1024 elems
constexpr int TILE_ELEMS = (BM + 4 * BO) * BK;  // 5120 elems per stage
constexpr int NVEC = TILE_ELEMS / 8;         // 640 8-elem slots per stage

typedef unsigned short u16;
typedef u16    u16x8  __attribute__((ext_vector_type(8)));
typedef __bf16 bf16x8 __attribute__((ext_vector_type(8)));
typedef float  f32x4  __attribute__((ext_vector_type(4)));

__device__ __forceinline__ u16 f2bits(float f) {   // f32 -> bf16 bits, RNE
  union { float f; unsigned int u; } v; v.f = f;
  unsigned int u = v.u;
  unsigned int r = u + 0x7fffu + ((u >> 16) & 1u);
  return (u16)(r >> 16);
}

__global__ __launch_bounds__(256)
void PhaseLinear_kernel(const float* __restrict__ inp, const float* __restrict__ ph,
                        const float* __restrict__ wts, const float* __restrict__ bia,
                        float* __restrict__ outp) {
  // double-buffered bf16 staging tile: [A (32x32) | W (128x32)] rows k-contig
  __shared__ alignas(16) u16 sT[2][TILE_ELEMS];   // 2 x 10 KB
  __shared__ float sCoef[BM][4];

  const int tid = threadIdx.x;
  const int wv  = tid >> 6;        // wave 0..3
  const int wo  = wv & 1;          // o-half (16 outs)
  const int wm  = wv >> 1;         // m-half (16 rows)
  const int l   = tid & 63;
  const int o0  = blockIdx.x * BO;
  const int b0  = blockIdx.y * BM;

  // --- spline coefficients (replicates reference tt=[1,t^2,t^3,0] bug) ---
  if (tid < BM) {
    const float PI = 3.14159265358979323846f;
    float p  = ph[b0 + tid];
    float t  = (p < 1.5f * PI) ? (p / (1.5f * PI)) : ((p - 0.5f * PI) / (1.5f * PI));
    float t2 = t * t, t3 = t2 * t;
    sCoef[tid][0] = t3 - 0.5f * t2;        // tt @ (0.5*CATMULL_ROM_BASIS)
    sCoef[tid][1] = 1.0f - 2.5f * t3;
    sCoef[tid][2] = 0.5f * t2 + 2.0f * t3;
    sCoef[tid][3] = -0.5f * t3;
  }

  // --- per-thread staging slots: slot v covers LDS elems [v*8, v*8+8) ---
  // thread t owns v = t, t+256 (+ t+512 if t<128): 640 slots total
  const int nv = (tid < NVEC - 512) ? 3 : 2;
  const float* src[3];
  int loff[3];
#pragma unroll
  for (int j = 0; j < 3; ++j) {
    int v = tid + j * 256;
    if (v >= NVEC) { src[j] = inp; loff[j] = 0; continue; }   // unused slot
    int e = v * 8;
    loff[j] = e;
    if (e < A_ELEMS) {                       // A region: input rows
      int row = e >> 5, col = e & 31;
      src[j] = inp + (size_t)(b0 + row) * IN_F + col;
    } else {                                 // W region: (c, o) rows
      int ep = e - A_ELEMS;
      int r = ep >> 5, col = ep & 31;        // r in 0..127
      int c = r >> 5, oo = r & 31;
      src[j] = wts + ((size_t)c * OUT_F + o0 + oo) * IN_F + col;
    }
  }

  // prefetch K-step 0 (f32) into registers
  f32x4 regs[3][2];
#pragma unroll
  for (int j = 0; j < 3; ++j)
    if (j < nv) {
      regs[j][0] = *(const f32x4*)(src[j]);
      regs[j][1] = *(const f32x4*)(src[j] + 4);
    }

  f32x4 acc[4];                    // [ctrl-pt], one 16-row m-frag per wave
#pragma unroll
  for (int c = 0; c < 4; ++c) acc[c] = (f32x4){0.f, 0.f, 0.f, 0.f};

  const int q = l >> 4;    // k-quad
  const int n = l & 15;    // M index (A) / N index (B) / col of C

  for (int kk = 0; kk < KITERS; ++kk) {
    const int bsel = kk & 1;
    u16* buf = &sT[bsel][0];
    // convert f32 -> bf16 (RNE) and store to LDS
#pragma unroll
    for (int j = 0; j < 3; ++j)
      if (j < nv) {
        u16x8 pk;
#pragma unroll
        for (int x = 0; x < 4; ++x) {
          pk[x]     = f2bits(regs[j][0][x]);
          pk[x + 4] = f2bits(regs[j][1][x]);
        }
        *(u16x8*)(buf + loff[j]) = pk;
      }
    // issue next step's global loads (latency hidden behind barrier+MFMA)
    if (kk + 1 < KITERS) {
#pragma unroll
      for (int j = 0; j < 3; ++j)
        if (j < nv) {
          regs[j][0] = *(const f32x4*)(src[j] + (kk + 1) * BK);
          regs[j][1] = *(const f32x4*)(src[j] + (kk + 1) * BK + 4);
        }
    }
    __syncthreads();                         // buf fully written by all waves
    const u16* pA = buf;                     // 32 rows x 32
    const u16* pW = buf + A_ELEMS;           // 128 rows x 32
    bf16x8 a0 = *(const bf16x8*)(pA + (wm * 16 + n) * BK + q * 8);
#pragma unroll
    for (int c = 0; c < 4; ++c) {
      bf16x8 wf = *(const bf16x8*)(pW + (c * 32 + wo * 16 + n) * BK + q * 8);
      acc[c] = __builtin_amdgcn_mfma_f32_16x16x32_bf16(a0, wf, acc[c], 0, 0, 0);
    }
    // no trailing barrier: next iter writes the OTHER buffer; passing the
    // next barrier implies every wave drained these ds_reads (lgkmcnt(0))
  }

  // --- epilogue: blend 4 control points + bias, f32 store ---
  // C/D layout (m89/m91 verified): col = l&15, row = (l>>4)*4 + reg
  const int o = o0 + wo * 16 + n;
  float bs[4];
#pragma unroll
  for (int c = 0; c < 4; ++c) bs[c] = bia[c * OUT_F + o];

#pragma unroll
  for (int r = 0; r < 4; ++r) {
    const int bl = wm * 16 + q * 4 + r;      // row within 32-row b-tile
    float v = 0.f;
#pragma unroll
    for (int c = 0; c < 4; ++c)
      v += sCoef[bl][c] * (acc[c][r] + bs[c]);
    outp[(size_t)(b0 + bl) * OUT_F + o] = v;
  }
}

extern "C" void kernel_launch(void* const* d_in, const int* in_sizes, int n_in,
                              void* d_out, int out_size, void* d_ws, size_t ws_size,
                              hipStream_t stream) {
  const float* inp = (const float*)d_in[0];   // input  (1024, 512) f32
  const float* ph  = (const float*)d_in[1];   // phase  (1024,)     f32
  const float* wts = (const float*)d_in[2];   // weights(4,512,512) f32
  const float* bia = (const float*)d_in[3];   // biases (4,512)     f32
  float* outp = (float*)d_out;                // out    (1024,512)  f32

  dim3 grid(OUT_F / BO, BATCH / BM);          // (16, 32) = 512 blocks, 2/CU
  PhaseLinear_kernel<<<grid, 256, 0, stream>>>(inp, ph, wts, bia, outp);
}

// Round 10
// 71.968 us; speedup vs baseline: 1.1594x; 1.0096x over previous
//
#include <hip/hip_runtime.h>

// PhaseLinear: out[b,o] = sum_c coef[b,c] * (sum_i in[b,i]*W[c,o,i] + bias[c,o])
// All-f32 in / f32 out, bf16 MFMA internally (absmax 0.031).
// Round 10: 16 waves/CU via K-split. Tile BM=32 x BO=16, grid (32,32)=1024
// blocks x 256 thr = 4 blocks/CU. Within a block, wave (wm,ks) computes
// m-half wm over K-window ks (256 each, 8 K-steps); pair-reduce via LDS.
// r9's verified coalesced LDS staging + double buffer retained.

#define BATCH 1024
#define IN_F  512
#define OUT_F 512

constexpr int BM = 32;                       // batch rows per block
constexpr int BO = 16;                       // out features per block
constexpr int BK = 32;                       // K per stage per window
constexpr int KW = IN_F / 2;                 // K-window size (256)
constexpr int KITERS = KW / BK;              // 8 steps
constexpr int A_ELEMS = 2 * BM * BK;         // 2048 (both windows)
constexpr int W_ELEMS = 2 * 4 * BO * BK;     // 4096
constexpr int TILE_ELEMS = A_ELEMS + W_ELEMS;   // 6144 elems per stage
constexpr int NVEC = TILE_ELEMS / 8;         // 768 slots -> 3 per thread

typedef unsigned short u16;
typedef u16    u16x8  __attribute__((ext_vector_type(8)));
typedef __bf16 bf16x8 __attribute__((ext_vector_type(8)));
typedef float  f32x4  __attribute__((ext_vector_type(4)));

__device__ __forceinline__ u16 f2bits(float f) {   // f32 -> bf16 bits, RNE
  union { float f; unsigned int u; } v; v.f = f;
  unsigned int u = v.u;
  unsigned int r = u + 0x7fffu + ((u >> 16) & 1u);
  return (u16)(r >> 16);
}

__global__ __launch_bounds__(256)
void PhaseLinear_kernel(const float* __restrict__ inp, const float* __restrict__ ph,
                        const float* __restrict__ wts, const float* __restrict__ bia,
                        float* __restrict__ outp) {
  // stage layout: A[w][row][32] (2048) | W[w][c][oo][32] (4096), bf16
  __shared__ alignas(16) u16 sT[2][TILE_ELEMS];   // 2 x 12 KB
  __shared__ float sCoef[BM][4];
  __shared__ float sRed[2][64][16];               // ks=1 partials, 8 KB

  const int tid = threadIdx.x;
  const int wv  = tid >> 6;        // wave 0..3
  const int wm  = wv & 1;          // m-half (16 rows)
  const int ks  = wv >> 1;         // K-window (0/1)
  const int l   = tid & 63;
  const int o0  = blockIdx.x * BO;
  const int b0  = blockIdx.y * BM;

  // --- spline coefficients (replicates reference tt=[1,t^2,t^3,0] bug) ---
  if (tid < BM) {
    const float PI = 3.14159265358979323846f;
    float p  = ph[b0 + tid];
    float t  = (p < 1.5f * PI) ? (p / (1.5f * PI)) : ((p - 0.5f * PI) / (1.5f * PI));
    float t2 = t * t, t3 = t2 * t;
    sCoef[tid][0] = t3 - 0.5f * t2;        // tt @ (0.5*CATMULL_ROM_BASIS)
    sCoef[tid][1] = 1.0f - 2.5f * t3;
    sCoef[tid][2] = 0.5f * t2 + 2.0f * t3;
    sCoef[tid][3] = -0.5f * t3;
  }

  // --- staging slots: slot v covers LDS elems [v*8, v*8+8); 3 per thread ---
  const float* src[3];
  int loff[3];
#pragma unroll
  for (int j = 0; j < 3; ++j) {
    int v = tid + j * 256;
    int e = v * 8;
    loff[j] = e;
    if (e < A_ELEMS) {                       // A[w][row][32]
      int w = e >> 10, rem = e & 1023;
      int row = rem >> 5, k = rem & 31;
      src[j] = inp + (size_t)(b0 + row) * IN_F + w * KW + k;
    } else {                                 // W[w][c][oo][32]
      int e2 = e - A_ELEMS;
      int w = e2 >> 11, rem = e2 & 2047;
      int r = rem >> 5, k = rem & 31;        // r: 0..63
      int c = r >> 4, oo = r & 15;
      src[j] = wts + ((size_t)c * OUT_F + o0 + oo) * IN_F + w * KW + k;
    }
  }

  // prefetch K-step 0 (f32) into registers
  f32x4 regs[3][2];
#pragma unroll
  for (int j = 0; j < 3; ++j) {
    regs[j][0] = *(const f32x4*)(src[j]);
    regs[j][1] = *(const f32x4*)(src[j] + 4);
  }

  f32x4 acc[4];                    // [ctrl-pt]
#pragma unroll
  for (int c = 0; c < 4; ++c) acc[c] = (f32x4){0.f, 0.f, 0.f, 0.f};

  const int q = l >> 4;    // k-quad
  const int n = l & 15;    // M index (A) / N index (B) / col of C

  for (int kk = 0; kk < KITERS; ++kk) {
    const int bsel = kk & 1;
    u16* buf = &sT[bsel][0];
    // convert f32 -> bf16 (RNE) and store to LDS
#pragma unroll
    for (int j = 0; j < 3; ++j) {
      u16x8 pk;
#pragma unroll
      for (int x = 0; x < 4; ++x) {
        pk[x]     = f2bits(regs[j][0][x]);
        pk[x + 4] = f2bits(regs[j][1][x]);
      }
      *(u16x8*)(buf + loff[j]) = pk;
    }
    // issue next step's global loads
    if (kk + 1 < KITERS) {
#pragma unroll
      for (int j = 0; j < 3; ++j) {
        regs[j][0] = *(const f32x4*)(src[j] + (kk + 1) * BK);
        regs[j][1] = *(const f32x4*)(src[j] + (kk + 1) * BK + 4);
      }
    }
    __syncthreads();                         // buf fully written by all waves
    // A frag: window ks, row wm*16+n; W frag: window ks, c, oo=n
    bf16x8 a0 = *(const bf16x8*)(buf + ks * 1024 + (wm * 16 + n) * BK + q * 8);
    const u16* pW = buf + A_ELEMS + ks * 2048;
#pragma unroll
    for (int c = 0; c < 4; ++c) {
      bf16x8 wf = *(const bf16x8*)(pW + c * 512 + n * BK + q * 8);
      acc[c] = __builtin_amdgcn_mfma_f32_16x16x32_bf16(a0, wf, acc[c], 0, 0, 0);
    }
    // no trailing barrier: next iter writes the OTHER buffer
  }

  // --- K-split pair reduction: ks=1 waves publish partials ---
  if (ks == 1) {
#pragma unroll
    for (int c = 0; c < 4; ++c)
#pragma unroll
      for (int r = 0; r < 4; ++r) sRed[wm][l][c * 4 + r] = acc[c][r];
  }
  __syncthreads();
  if (ks == 0) {
    // --- epilogue: combine halves, blend 4 control points + bias ---
    // C/D layout (m89/m91 verified): col = l&15, row = (l>>4)*4 + reg
    const int o = o0 + n;
    float bs[4];
#pragma unroll
    for (int c = 0; c < 4; ++c) bs[c] = bia[c * OUT_F + o];

#pragma unroll
    for (int r = 0; r < 4; ++r) {
      const int bl = wm * 16 + q * 4 + r;    // row within 32-row b-tile
      float v = 0.f;
#pragma unroll
      for (int c = 0; c < 4; ++c) {
        float s = acc[c][r] + sRed[wm][l][c * 4 + r];
        v += sCoef[bl][c] * (s + bs[c]);
      }
      outp[(size_t)(b0 + bl) * OUT_F + o] = v;
    }
  }
}

extern "C" void kernel_launch(void* const* d_in, const int* in_sizes, int n_in,
                              void* d_out, int out_size, void* d_ws, size_t ws_size,
                              hipStream_t stream) {
  const float* inp = (const float*)d_in[0];   // input  (1024, 512) f32
  const float* ph  = (const float*)d_in[1];   // phase  (1024,)     f32
  const float* wts = (const float*)d_in[2];   // weights(4,512,512) f32
  const float* bia = (const float*)d_in[3];   // biases (4,512)     f32
  float* outp = (float*)d_out;                // out    (1024,512)  f32

  dim3 grid(OUT_F / BO, BATCH / BM);          // (32, 32) = 1024 blocks, 4/CU
  PhaseLinear_kernel<<<grid, 256, 0, stream>>>(inp, ph, wts, bia, outp);
}